// Round 4
// baseline (56.304 us; speedup 1.0000x reference)
//
#include <hip/hip_runtime.h>

// Locally-connected 2D: out[b,o,y,x] = sum_{c,kh,kw} x[b,c,y+kh,x+kw] * W[y,x,o,c*25+kh*5+kw] + b[y,x,o]
// x: [128,3,64,64] f32, W: [60,60,32,75] f32, bias: [60,60,32] f32, out: [128,32,60,60] f32.
//
// Phase 1 (k1): per-position GEMM M=128,N=32,K=75 via bf16 MFMA. One block = one (y, x-pair).
// K re-indexed to k' = c*30+kh*6+w so both x positions share the A (patch) matrix;
// W staged as 2 shift-padded copies in LDS. K'=90 pad 96 -> 3 MFMA K-steps.
// Register-first staging (issue-early/write-late), W scatter via 75-entry perm LUT
// (slot = (k/75)*KLD + plut[k%75]; round-3 bug was a 300-entry LUT for a 2400-wide k).
// Epilogue writes tmp[pos][b*32+o][xi] (full-cache-line wave stores); k2 transposes to out.

#define RY 60
#define RX 60
#define OC 32
#define BATCH 128
#define CIN 3
#define HW 64
#define KLD 104   // bf16 row stride: 208 B = 13*16 B -> 2-way-max bank aliasing on b128 reads
#define XT 2      // x positions per block

typedef __attribute__((ext_vector_type(8))) short short8;
typedef __attribute__((ext_vector_type(4))) float f32x4;

__device__ __forceinline__ ushort bf16r(float f) {
    union { float f; unsigned u; } v; v.f = f;
    return (ushort)((v.u + 0x7FFFu + ((v.u >> 16) & 1u)) >> 16);  // RNE
}

template<bool COAL>
__global__ __launch_bounds__(256, 4) void lc2d_k1(
    const float* __restrict__ x, const float* __restrict__ w,
    const float* __restrict__ bias, float* __restrict__ outp,
    float* __restrict__ tmp)
{
    __shared__ ushort pa[BATCH][KLD];    // 26624 B
    __shared__ ushort wt[XT][OC][KLD];   // 13312 B
    __shared__ float  bl[XT][OC];        // 256 B
    __shared__ ushort plut[80];          // 160 B; total 40352 -> 4 blocks/CU

    const int tid = threadIdx.x;
    // XCD-chunked block mapping: 1800 = 8 x 225, xp-major within chunk (bijective).
    const int id  = blockIdx.x;
    const int lin = (id & 7) * 225 + (id >> 3);
    const int xp  = lin % 30;
    const int y   = lin / 30;
    const int x0  = xp * XT;

    // ================= issue ALL global loads first (into registers) =================
    float4 wr[5];                         // 1200 float4 of W across 256 threads
    #pragma unroll
    for (int m = 0; m < 5; ++m) {
        const int idx = tid + 256 * m;
        if (idx < 1200) {
            const int xi = idx >= 600 ? 1 : 0;
            const int i2 = idx - 600 * xi;
            wr[m] = *(const float4*)(w + (size_t)(y * RX + x0 + xi) * (OC * 75) + i2 * 4);
        }
    }
    float2 pr[8][3];                      // 1920 patch rows x 6 floats
    #pragma unroll
    for (int m = 0; m < 8; ++m) {
        const int r = tid + 256 * m;
        if (r < 1920) {
            const int b  = r / 15;
            const int cm = r % 15;
            const int c  = cm / 5;
            const int kh = cm % 5;
            const float* src = x + (size_t)((b * CIN + c) * HW + (y + kh)) * HW + x0;
            pr[m][0] = *(const float2*)(src);
            pr[m][1] = *(const float2*)(src + 2);
            pr[m][2] = *(const float2*)(src + 4);
        }
    }
    float bv = 0.f;
    if (tid < XT * OC)
        bv = bias[(size_t)(y * RX + x0 + (tid >> 5)) * OC + (tid & 31)];

    // ============== overlap latency: zero wt + pa tail, build perm LUT ==============
    {
        uint4* wz = (uint4*)&wt[0][0][0];
        for (int i = tid; i < XT * OC * KLD / 8; i += 256) wz[i] = (uint4){0u, 0u, 0u, 0u};
        for (int i = tid; i < BATCH * 3; i += 256) {
            int b = i / 3, j = i % 3;
            ((unsigned*)&pa[b][90])[j] = 0u;   // zero k' in [90,96)
        }
        if (tid < 75) {
            const int c  = tid / 25;
            const int rm = tid % 25;
            const int kh = rm / 5;
            const int kw = rm % 5;
            plut[tid] = (ushort)(c * 30 + kh * 6 + kw);
        }
    }
    if (tid < XT * OC) bl[tid >> 5][tid & 31] = bv;
    __syncthreads();

    // ================= scatter W from registers via perm LUT =================
    {
        ushort* wtf = &wt[0][0][0];
        #pragma unroll
        for (int m = 0; m < 5; ++m) {
            const int idx = tid + 256 * m;
            if (idx < 1200) {
                const int xi = idx >= 600 ? 1 : 0;
                const int i2 = idx - 600 * xi;
                const int kb = i2 * 4;
                ushort* base = wtf + xi * (OC * KLD) + xi;   // +xi = shift pad
                #pragma unroll
                for (int j = 0; j < 4; ++j) {
                    const int k  = kb + j;
                    const int o  = k / 75;          // magic-mul
                    const int km = k - o * 75;
                    const float val = (j == 0) ? wr[m].x : (j == 1) ? wr[m].y
                                    : (j == 2) ? wr[m].z : wr[m].w;
                    base[o * KLD + plut[km]] = bf16r(val);
                }
            }
        }
    }
    // ================= scatter patches from registers =================
    #pragma unroll
    for (int m = 0; m < 8; ++m) {
        const int r = tid + 256 * m;
        if (r < 1920) {
            const int b  = r / 15;
            const int cm = r % 15;
            const int c  = cm / 5;
            const int kh = cm % 5;
            unsigned* dst = (unsigned*)&pa[b][c * 30 + kh * 6];
            dst[0] = (unsigned)bf16r(pr[m][0].x) | ((unsigned)bf16r(pr[m][0].y) << 16);
            dst[1] = (unsigned)bf16r(pr[m][1].x) | ((unsigned)bf16r(pr[m][1].y) << 16);
            dst[2] = (unsigned)bf16r(pr[m][2].x) | ((unsigned)bf16r(pr[m][2].y) << 16);
        }
    }
    __syncthreads();

    // ================= MFMA: wave wid owns rows [wid*32, +32) x 2 N-tiles x 2 xi =================
    const int wid  = tid >> 6;
    const int lane = tid & 63;
    const int lrow = lane & 15;
    const int lgrp = lane >> 4;
    const int mbase = wid * 32;

    f32x4 acc[2][2][2];                // [mt][nt][xi]
    #pragma unroll
    for (int mt = 0; mt < 2; ++mt)
        #pragma unroll
        for (int nt = 0; nt < 2; ++nt)
            #pragma unroll
            for (int xi = 0; xi < 2; ++xi)
                acc[mt][nt][xi] = (f32x4){0.f, 0.f, 0.f, 0.f};

    #pragma unroll
    for (int ks = 0; ks < 3; ++ks) {
        const int koff = ks * 32 + lgrp * 8;
        const short8 af0 = *(const short8*)&pa[mbase + lrow][koff];
        const short8 af1 = *(const short8*)&pa[mbase + 16 + lrow][koff];
        const short8 b00 = *(const short8*)&wt[0][lrow][koff];
        const short8 b10 = *(const short8*)&wt[1][lrow][koff];
        const short8 b01 = *(const short8*)&wt[0][16 + lrow][koff];
        const short8 b11 = *(const short8*)&wt[1][16 + lrow][koff];
        acc[0][0][0] = __builtin_amdgcn_mfma_f32_16x16x32_bf16(af0, b00, acc[0][0][0], 0, 0, 0);
        acc[0][0][1] = __builtin_amdgcn_mfma_f32_16x16x32_bf16(af0, b10, acc[0][0][1], 0, 0, 0);
        acc[0][1][0] = __builtin_amdgcn_mfma_f32_16x16x32_bf16(af0, b01, acc[0][1][0], 0, 0, 0);
        acc[0][1][1] = __builtin_amdgcn_mfma_f32_16x16x32_bf16(af0, b11, acc[0][1][1], 0, 0, 0);
        acc[1][0][0] = __builtin_amdgcn_mfma_f32_16x16x32_bf16(af1, b00, acc[1][0][0], 0, 0, 0);
        acc[1][0][1] = __builtin_amdgcn_mfma_f32_16x16x32_bf16(af1, b10, acc[1][0][1], 0, 0, 0);
        acc[1][1][0] = __builtin_amdgcn_mfma_f32_16x16x32_bf16(af1, b01, acc[1][1][0], 0, 0, 0);
        acc[1][1][1] = __builtin_amdgcn_mfma_f32_16x16x32_bf16(af1, b11, acc[1][1][1], 0, 0, 0);
    }

    if (COAL) {
        // tmp[pos_pair][b*32+o][xi]: wave store = 4 x 128B full-line chunks
        float* tbase = tmp + (size_t)(y * 30 + xp) * (BATCH * OC * XT);
        #pragma unroll
        for (int mt = 0; mt < 2; ++mt) {
            #pragma unroll
            for (int nt = 0; nt < 2; ++nt) {
                const int o = nt * 16 + lrow;
                const float bv0 = bl[0][o];
                const float bv1 = bl[1][o];
                #pragma unroll
                for (int r = 0; r < 4; ++r) {
                    const int b = mbase + mt * 16 + lgrp * 4 + r;
                    float2 v;
                    v.x = acc[mt][nt][0][r] + bv0;
                    v.y = acc[mt][nt][1][r] + bv1;
                    *(float2*)(tbase + (size_t)(b * OC + o) * 2) = v;
                }
            }
        }
    } else {
        const int pos = y * RX + x0;
        #pragma unroll
        for (int mt = 0; mt < 2; ++mt) {
            #pragma unroll
            for (int nt = 0; nt < 2; ++nt) {
                const int o = nt * 16 + lrow;
                const float bv0 = bl[0][o];
                const float bv1 = bl[1][o];
                const int brow = mbase + mt * 16 + lgrp * 4;
                #pragma unroll
                for (int r = 0; r < 4; ++r) {
                    float2 v;
                    v.x = acc[mt][nt][0][r] + bv0;
                    v.y = acc[mt][nt][1][r] + bv1;
                    *(float2*)(outp + (size_t)((brow + r) * OC + o) * (RY * RX) + pos) = v;
                }
            }
        }
    }
}

// Phase 2: tmp[y][xp][c][xi] -> out[c][y*60 + xp*2+xi], c = b*32+o in [0,4096)
__global__ __launch_bounds__(256) void lc2d_k2(
    const float* __restrict__ tmp, float* __restrict__ out)
{
    __shared__ float tile[64][65];
    const int y  = blockIdx.y;
    const int cb = blockIdx.x * 64;

    for (int i = threadIdx.x; i < 30 * 32; i += 256) {
        const int xp = i >> 5;
        const int cp = i & 31;
        const float4 v = *(const float4*)(tmp + ((size_t)(y * 30 + xp) * 4096 + cb + cp * 2) * 2);
        tile[cp * 2][xp * 2]         = v.x;
        tile[cp * 2][xp * 2 + 1]     = v.y;
        tile[cp * 2 + 1][xp * 2]     = v.z;
        tile[cp * 2 + 1][xp * 2 + 1] = v.w;
    }
    __syncthreads();

    for (int i = threadIdx.x; i < 64 * 60; i += 256) {
        const int cl = i / 60;
        const int xx = i % 60;
        out[(size_t)(cb + cl) * (RY * RX) + y * RX + xx] = tile[cl][xx];
    }
}

extern "C" void kernel_launch(void* const* d_in, const int* in_sizes, int n_in,
                              void* d_out, int out_size, void* d_ws, size_t ws_size,
                              hipStream_t stream) {
    const float* x    = (const float*)d_in[0];
    const float* w    = (const float*)d_in[1];
    const float* bias = (const float*)d_in[2];
    float* out        = (float*)d_out;
    float* tmp        = (float*)d_ws;

    const size_t tmp_bytes = (size_t)RY * RX * BATCH * OC * sizeof(float); // 59 MB

    if (ws_size >= tmp_bytes) {
        lc2d_k1<true><<<1800, 256, 0, stream>>>(x, w, bias, out, tmp);
        lc2d_k2<<<dim3(64, 60), 256, 0, stream>>>(tmp, out);
    } else {
        lc2d_k1<false><<<1800, 256, 0, stream>>>(x, w, bias, out, tmp);
    }
}